// Round 13
// baseline (184.417 us; speedup 1.0000x reference)
//
#include <hip/hip_runtime.h>
#include <math.h>

#define B_ 16
#define C_ 512
#define T_ 2048
#define K_ 4096
#define M_ (B_*T_)          // 32768 rows
#define MARGIN_ 0.5f

typedef float f32x4   __attribute__((ext_vector_type(4)));
typedef int   int32x4v __attribute__((ext_vector_type(4)));
typedef int   int32x8v __attribute__((ext_vector_type(8)));

static __device__ __forceinline__ unsigned int umin_(unsigned int a, unsigned int b) {
    return a < b ? a : b;
}
static __device__ __forceinline__ unsigned int umax_(unsigned int a, unsigned int b) {
    return a > b ? a : b;
}
// async global->LDS, 16B per lane. LDS dest = wave-uniform base + lane*16.
static __device__ __forceinline__ void gload_lds16(const void* g, void* l) {
    __builtin_amdgcn_global_load_lds(
        (const __attribute__((address_space(1))) unsigned int*)g,
        (__attribute__((address_space(3))) unsigned int*)l,
        16, 0, 0);
}

// float -> OCP e4m3fn, round-nearest-even, 448-saturating, |x|<2^-6 subnormal.
static __device__ __forceinline__ unsigned char f32_to_e4m3(float x) {
    unsigned int u = __float_as_uint(x);
    unsigned int sgn = (u >> 24) & 0x80u;
    unsigned int ax = u & 0x7FFFFFFFu;
    if (ax >= 0x43E00000u) return (unsigned char)(sgn | 0x7Eu);   // >=448 -> 448
    if (ax < 0x3C800000u) {                                       // |x| < 2^-6
        int q = (int)rintf(__uint_as_float(ax) * 512.0f);         // units 2^-9, RNE
        if (q >= 8) return (unsigned char)(sgn | 0x08u);          // -> 2^-6
        return (unsigned char)(sgn | (unsigned)q);
    }
    unsigned int b = ax + 0x7FFFFu + ((ax >> 20) & 1u);           // RNE @ 3 mant bits
    unsigned int e = b >> 23;
    unsigned int m = (b >> 20) & 7u;
    int e4 = (int)e - 127 + 7;
    if (e4 >= 16) return (unsigned char)(sgn | 0x7Eu);            // rounded past 448
    return (unsigned char)(sgn | ((unsigned)e4 << 3) | m);
}

// ---------------------------------------------------------------------------
// pack_A: student (B,C,T) fp32 -> Apack[M][512] fp8 e4m3, PLAIN layout
// (k-contiguous; scaled MFMA lane reads its own 32-B k-block directly).
// 64x64 transpose tiles through LDS.
// ---------------------------------------------------------------------------
__global__ __launch_bounds__(256) void packA_kernel(
    const float* __restrict__ student, unsigned char* __restrict__ Apack)
{
    __shared__ float ts[64][65];
    const int tid = threadIdx.x;
    const int t0 = blockIdx.x * 64;
    const int c0 = blockIdx.y * 64;
    const int b  = blockIdx.z;

#pragma unroll
    for (int r = 0; r < 4; ++r) {
        int f  = tid + r * 256;
        int i  = f >> 4;                          // c row 0..63
        int j4 = (f & 15) << 2;                   // t col 0..60
        float4 v = *reinterpret_cast<const float4*>(
            student + ((size_t)(b * C_ + c0 + i)) * T_ + (t0 + j4));
        *reinterpret_cast<float4*>(&ts[i][j4]) = v;
    }
    __syncthreads();

#pragma unroll
    for (int r = 0; r < 2; ++r) {
        int f  = tid + r * 256;                   // 0..511
        int j  = f >> 3;                          // t row 0..63
        int pi = f & 7;                           // 8-byte piece within group
        unsigned long long w = 0ull;
#pragma unroll
        for (int u = 0; u < 8; ++u) {
            unsigned long long byte8 = (unsigned long long)f32_to_e4m3(ts[pi * 8 + u][j]);
            w |= byte8 << (8 * u);
        }
        *reinterpret_cast<unsigned long long*>(
            Apack + (size_t)(b * T_ + t0 + j) * 512 + c0 + pi * 8) = w;
    }
}

// ---------------------------------------------------------------------------
// pack_B + scaled-biased norms: codebook (K,C) fp32 -> Bpack[K][512] fp8
// (plain layout), cbnb256[k] = (||c_k||^2 + 1024) * 256.
// ---------------------------------------------------------------------------
__global__ __launch_bounds__(256) void packB_norm_kernel(
    const float* __restrict__ cb, unsigned char* __restrict__ Bpack,
    float* __restrict__ cbnb256)
{
    int code = blockIdx.x * 4 + (threadIdx.x >> 6);
    int lane = threadIdx.x & 63;
    const float* row = cb + (size_t)code * C_;
    unsigned char* orow = Bpack + (size_t)code * 512;

    int c = lane * 8;
    float4 v0 = *reinterpret_cast<const float4*>(row + c);
    float4 v1 = *reinterpret_cast<const float4*>(row + c + 4);
    float s = v0.x*v0.x + v0.y*v0.y + v0.z*v0.z + v0.w*v0.w
            + v1.x*v1.x + v1.y*v1.y + v1.z*v1.z + v1.w*v1.w;
    unsigned long long w =
          (unsigned long long)f32_to_e4m3(v0.x)
        | ((unsigned long long)f32_to_e4m3(v0.y) << 8)
        | ((unsigned long long)f32_to_e4m3(v0.z) << 16)
        | ((unsigned long long)f32_to_e4m3(v0.w) << 24)
        | ((unsigned long long)f32_to_e4m3(v1.x) << 32)
        | ((unsigned long long)f32_to_e4m3(v1.y) << 40)
        | ((unsigned long long)f32_to_e4m3(v1.z) << 48)
        | ((unsigned long long)f32_to_e4m3(v1.w) << 56);
    *reinterpret_cast<unsigned long long*>(orow + c) = w;

#pragma unroll
    for (int off = 32; off; off >>= 1) s += __shfl_down(s, off);
    if (lane == 0) cbnb256[code] = (s + 1024.0f) * 256.0f;
}

// ---------------------------------------------------------------------------
// MX-fp8 screen: mfma_scale_f32_16x16x128_f8f6f4 with scale = E8M0(127) = 1.0
// (bit-exact same math as non-scaled fp8, 2.27x the MFMA rate -- m21).
//   score256(m,k) = (||c_k||^2 + 1024)*256 - 512*(z8 . c8)
//   packed        = ((uint)score256 << 12) | k
// Structure: B-PANEL-RESIDENT.  Per code-tile ct (128 codes):
//   barrier; stage 128x512B B-panel into LDS (gload_lds16, pre-swizzled
//   global source, linear dest); barrier;  then 4 segs x {per-lane A loads
//   (global->reg, no LDS, no barrier), 8 ds_read_b128 from panel, 16 scaled
//   MFMAs}.  Barriers: 16 total (vs 32 in R12); no manual vmcnt -- the only
//   cross-wave LDS traffic is the panel, guarded by __syncthreads.
// A loads: lane (lr,lk) reads rows m0+wm*64+i*16+lr, bytes seg*128+lk*32
//   (lane-quads form whole 128-B lines; A is re-read 8x, XCD-grouped L2-hot).
// Panel swizzle: slot(16B) ^= row&7 -> quarter-wave 2-way max (free, m136).
// Operand layout (gfx950 f8f6f4): lane l holds k = (l>>4)*32 + [0..32) as 8
//   VGPRs, bytes ascending; C/D layout shape-determined (same as 16x16x32).
// Grid: flat 1024, XCD-bijective swizzle.  __launch_bounds__(256,2): R8-R10
//   lesson (no bound -> 64-VGPR spill; tight budget -> remat storm).
// ---------------------------------------------------------------------------
__global__ __launch_bounds__(256, 2) void screen_kernel(
    const unsigned char* __restrict__ Apack,
    const unsigned char* __restrict__ Bpack,
    const float* __restrict__ cbnb256,
    uint2* __restrict__ out2)                      // [8 streams][M]
{
    __shared__ __align__(16) unsigned char bpanel[128 * 512];   // 64 KB
    __shared__ float cbnb_lds[1024];                            // 4 KB

    const int tid = threadIdx.x;
    const int l   = tid & 63;
    const int wv  = tid >> 6;
    const int wm  = wv >> 1, wn = wv & 1;
    const int lr  = l & 15;
    const int lk  = l >> 4;

    // XCD-bijective block swizzle (1024 blocks, 8 XCDs, 128 each)
    const int bid = blockIdx.x;
    const int wg  = (bid & 7) * 128 + (bid >> 3);
    const int q   = wg & 3;
    const int m0  = (wg >> 2) * 128;

    // ---- cbnb -> LDS (landed by the first panel barrier)
    {
        float4 v = reinterpret_cast<const float4*>(cbnb256 + q * 1024)[tid];
        reinterpret_cast<float4*>(cbnb_lds)[tid] = v;
    }

    unsigned int u1[16], u2v[16];
#pragma unroll
    for (int e = 0; e < 16; ++e) { u1[e] = 0xFFFFFFFFu; u2v[e] = 0xFFFFFFFFu; }

    f32x4 acc[4][4];
#pragma unroll
    for (int i = 0; i < 4; ++i)
#pragma unroll
        for (int j = 0; j < 4; ++j) acc[i][j] = (f32x4)0.f;

    // A per-lane base: row = m0 + wm*64 + lr (+ i*16), byte lk*32 (+ seg*128)
    const unsigned char* pA = Apack + (size_t)(m0 + wm * 64 + lr) * 512 + lk * 32;

    // panel staging lane constants: instr covers rows Rbase, Rbase+1;
    // lane l -> row Rbase+(l>>5), linear lds slot l&31, global slot ^ (row&7)
    const int h  = l >> 5;
    const int s5 = l & 31;
    const unsigned char* Bq = Bpack + (size_t)q * 524288;

    auto fold = [&](int ct) {
        unsigned int kk4[4];
        float cnb[4];
#pragma unroll
        for (int j = 0; j < 4; ++j) {
            int kl = ct * 128 + wn * 64 + j * 16 + lr;
            kk4[j] = (unsigned int)(q * 1024 + kl);
            cnb[j] = cbnb_lds[kl];
        }
#pragma unroll
        for (int i = 0; i < 4; ++i)
#pragma unroll
            for (int r = 0; r < 4; ++r) {
                int e = i * 4 + r;
                unsigned int p[4];
#pragma unroll
                for (int j = 0; j < 4; ++j) {
                    float s = fmaf(-512.f, acc[i][j][r], cnb[j]);
                    s = fmaxf(s, 0.f);
                    p[j] = ((unsigned int)s << 12) | kk4[j];
                }
                unsigned int mn0 = umin_(p[0], p[1]), mx0 = umax_(p[0], p[1]);
                unsigned int mn1 = umin_(p[2], p[3]), mx1 = umax_(p[2], p[3]);
                unsigned int t0 = umax_(u1[e], mn0);
                u1[e]  = umin_(u1[e], mn0);
                u2v[e] = umin_(umin_(t0, u2v[e]), mx0);
                unsigned int t1 = umax_(u1[e], mn1);
                u1[e]  = umin_(u1[e], mn1);
                u2v[e] = umin_(umin_(t1, u2v[e]), mx1);
            }
#pragma unroll
        for (int i = 0; i < 4; ++i)
#pragma unroll
            for (int j = 0; j < 4; ++j) acc[i][j] = (f32x4)0.f;
    };

    for (int ct = 0; ct < 8; ++ct) {
        __syncthreads();              // previous panel's readers are done
        const unsigned char* Bct = Bq + (size_t)ct * 65536;
        // stage 128 x 512 B panel: wave wv covers rows [wv*32, wv*32+32)
#pragma unroll
        for (int r2 = 0; r2 < 16; ++r2) {
            int Rbase = wv * 32 + r2 * 2;
            int row   = Rbase + h;
            int goff  = (s5 ^ (row & 7)) * 16;
            gload_lds16(Bct + (size_t)row * 512 + goff, &bpanel[Rbase * 512]);
        }
        __syncthreads();              // implicit vmcnt(0): panel landed

#pragma unroll
        for (int seg = 0; seg < 4; ++seg) {
            int32x8v a[4], bb[4];
#pragma unroll
            for (int i = 0; i < 4; ++i)
                a[i] = *reinterpret_cast<const int32x8v*>(
                    pA + (size_t)i * 8192 + seg * 128);
#pragma unroll
            for (int j = 0; j < 4; ++j) {
                int br  = wn * 64 + j * 16 + lr;
                int key = br & 7;
                int g0  = seg * 8 + ((2 * lk) ^ key);
                int g1  = seg * 8 + ((2 * lk + 1) ^ key);
                const unsigned char* bp = &bpanel[br * 512];
                int32x4v blo = *reinterpret_cast<const int32x4v*>(bp + g0 * 16);
                int32x4v bhi = *reinterpret_cast<const int32x4v*>(bp + g1 * 16);
                bb[j] = __builtin_shufflevector(blo, bhi, 0, 1, 2, 3, 4, 5, 6, 7);
            }
#pragma unroll
            for (int i = 0; i < 4; ++i)
#pragma unroll
                for (int j = 0; j < 4; ++j)
                    acc[i][j] = __builtin_amdgcn_mfma_scale_f32_16x16x128_f8f6f4(
                        a[i], bb[j], acc[i][j], 0, 0, 0, 127, 0, 127);
        }
        fold(ct);
    }

    // ---- cross-lane top-2 merge over the 16 lr lanes
#pragma unroll
    for (int e = 0; e < 16; ++e) {
        unsigned int a1 = u1[e], a2 = u2v[e];
#pragma unroll
        for (int off = 1; off < 16; off <<= 1) {
            unsigned int b1 = (unsigned int)__shfl_xor((int)a1, off);
            unsigned int b2 = (unsigned int)__shfl_xor((int)a2, off);
            unsigned int m1 = umin_(a1, b1);
            a2 = umin_(umax_(a1, b1), umin_(a2, b2));
            a1 = m1;
        }
        u1[e] = a1; u2v[e] = a2;
    }

    if (lr == 0) {
        int cand = q * 2 + wn;
#pragma unroll
        for (int i = 0; i < 4; ++i)
#pragma unroll
            for (int r = 0; r < 4; ++r) {
                int m = m0 + wm * 64 + i * 16 + lk * 4 + r;
                out2[(size_t)cand * M_ + m] = make_uint2(u1[i * 4 + r], u2v[i * 4 + r]);
            }
    }
}

// ---------------------------------------------------------------------------
// fused combine + exact rescore + loss.  512 blocks x 256 threads; each block
// owns 64 rows, each wave (qw) covers a 128-channel quarter (wave-coalesced).
// Partial sums via LDS [4][64][5] (stride-5: 2-way max); wave 0 picks the
// candidate + reduces.  (R11: tail 75 -> 44 us.)
// ---------------------------------------------------------------------------
__global__ __launch_bounds__(256) void loss_kernel(
    const float* __restrict__ student, const float* __restrict__ teacher,
    const float* __restrict__ cb, const uint2* __restrict__ out2,
    const int* __restrict__ codes, float* __restrict__ partials)
{
    __shared__ float sh[4][64][5];

    const int l  = threadIdx.x & 63;               // row within block
    const int qw = threadIdx.x >> 6;               // channel quarter (wave id)
    const int m  = blockIdx.x * 64 + l;
    const int b  = m / T_;
    const int t  = m % T_;

    // inline combine of the 8 candidate streams (redundant across waves; cheap)
    uint2 g = out2[m];
#pragma unroll
    for (int c = 1; c < 8; ++c) {
        uint2 o = out2[(size_t)c * M_ + m];
        unsigned int m1 = umin_(g.x, o.x);
        g.y = umin_(umax_(g.x, o.x), umin_(g.y, o.y));
        g.x = m1;
    }
    const int k1 = (int)(g.x & 0xFFFu);
    const int k2 = (int)(g.y & 0xFFFu);

    const float* sp = student + (size_t)b * C_ * T_ + t;
    const float* tp = teacher + (size_t)b * C_ * T_ + t;
    const float4* c1p = reinterpret_cast<const float4*>(cb + (size_t)k1 * C_);
    const float4* c2p = reinterpret_cast<const float4*>(cb + (size_t)k2 * C_);

    float dp = 0.f, ds1 = 0.f, ds2 = 0.f, dt1 = 0.f, dt2 = 0.f;
    const int c4beg = qw * 32;                     // 32 float4-groups = 128 ch
#pragma unroll 4
    for (int c4 = c4beg; c4 < c4beg + 32; ++c4) {
        float4 cv1 = c1p[c4];
        float4 cv2 = c2p[c4];
        float a0 = tp[(size_t)(c4 * 4 + 0) * T_];
        float a1 = tp[(size_t)(c4 * 4 + 1) * T_];
        float a2 = tp[(size_t)(c4 * 4 + 2) * T_];
        float a3 = tp[(size_t)(c4 * 4 + 3) * T_];
        float p0 = sp[(size_t)(c4 * 4 + 0) * T_];
        float p1 = sp[(size_t)(c4 * 4 + 1) * T_];
        float p2 = sp[(size_t)(c4 * 4 + 2) * T_];
        float p3 = sp[(size_t)(c4 * 4 + 3) * T_];
        float e;
        e = a0 - p0;   dp  = fmaf(e, e, dp);
        e = a1 - p1;   dp  = fmaf(e, e, dp);
        e = a2 - p2;   dp  = fmaf(e, e, dp);
        e = a3 - p3;   dp  = fmaf(e, e, dp);
        e = p0 - cv1.x; ds1 = fmaf(e, e, ds1);
        e = p1 - cv1.y; ds1 = fmaf(e, e, ds1);
        e = p2 - cv1.z; ds1 = fmaf(e, e, ds1);
        e = p3 - cv1.w; ds1 = fmaf(e, e, ds1);
        e = p0 - cv2.x; ds2 = fmaf(e, e, ds2);
        e = p1 - cv2.y; ds2 = fmaf(e, e, ds2);
        e = p2 - cv2.z; ds2 = fmaf(e, e, ds2);
        e = p3 - cv2.w; ds2 = fmaf(e, e, ds2);
        e = a0 - cv1.x; dt1 = fmaf(e, e, dt1);
        e = a1 - cv1.y; dt1 = fmaf(e, e, dt1);
        e = a2 - cv1.z; dt1 = fmaf(e, e, dt1);
        e = a3 - cv1.w; dt1 = fmaf(e, e, dt1);
        e = a0 - cv2.x; dt2 = fmaf(e, e, dt2);
        e = a1 - cv2.y; dt2 = fmaf(e, e, dt2);
        e = a2 - cv2.z; dt2 = fmaf(e, e, dt2);
        e = a3 - cv2.w; dt2 = fmaf(e, e, dt2);
    }
    sh[qw][l][0] = dp;
    sh[qw][l][1] = ds1;
    sh[qw][l][2] = ds2;
    sh[qw][l][3] = dt1;
    sh[qw][l][4] = dt2;
    __syncthreads();

    if (qw == 0) {
        float S0 = 0.f, S1 = 0.f, S2 = 0.f, S3 = 0.f, S4 = 0.f;
#pragma unroll
        for (int w = 0; w < 4; ++w) {
            S0 += sh[w][l][0];
            S1 += sh[w][l][1];
            S2 += sh[w][l][2];
            S3 += sh[w][l][3];
            S4 += sh[w][l][4];
        }
        const int tc = codes[m];
        bool v1 = (k1 != tc), v2 = (k2 != tc);
        bool take2;
        if (!v1)      take2 = true;
        else if (!v2) take2 = false;
        else          take2 = (S2 < S1) || (S2 == S1 && k2 < k1);
        float dn = take2 ? S4 : S3;

        float dpos = sqrtf(S0);
        float dneg = sqrtf(dn);
        float loss = fmaxf(dpos - dneg + MARGIN_, 0.f);
        float ind  = (dneg > dpos + MARGIN_) ? 1.f : 0.f;

        float v0 = loss, vv1 = dpos, vv2 = dneg, vv3 = ind;
#pragma unroll
        for (int off = 32; off; off >>= 1) {
            v0  += __shfl_down(v0, off);
            vv1 += __shfl_down(vv1, off);
            vv2 += __shfl_down(vv2, off);
            vv3 += __shfl_down(vv3, off);
        }
        if (l == 0) {
            partials[blockIdx.x * 4 + 0] = v0;
            partials[blockIdx.x * 4 + 1] = vv1;
            partials[blockIdx.x * 4 + 2] = vv2;
            partials[blockIdx.x * 4 + 3] = vv3;
        }
    }
}

// ---------------------------------------------------------------------------
// final deterministic reduction of 512 partial rows -> 4 means.
// ---------------------------------------------------------------------------
__global__ __launch_bounds__(256) void final_kernel(
    const float* __restrict__ partials, float* __restrict__ out)
{
    __shared__ float sh[4][4];
    int tid = threadIdx.x;                         // 256 threads, 2 rows each
    float s0 = partials[tid * 4 + 0] + partials[(tid + 256) * 4 + 0];
    float s1 = partials[tid * 4 + 1] + partials[(tid + 256) * 4 + 1];
    float s2 = partials[tid * 4 + 2] + partials[(tid + 256) * 4 + 2];
    float s3 = partials[tid * 4 + 3] + partials[(tid + 256) * 4 + 3];
#pragma unroll
    for (int off = 32; off; off >>= 1) {
        s0 += __shfl_down(s0, off);
        s1 += __shfl_down(s1, off);
        s2 += __shfl_down(s2, off);
        s3 += __shfl_down(s3, off);
    }
    int w = tid >> 6, lane = tid & 63;
    if (lane == 0) { sh[w][0] = s0; sh[w][1] = s1; sh[w][2] = s2; sh[w][3] = s3; }
    __syncthreads();
    if (tid == 0) {
        const float inv = 1.0f / (float)M_;
        float o0 = 0.f, o1 = 0.f, o2 = 0.f, o3 = 0.f;
#pragma unroll
        for (int ww = 0; ww < 4; ++ww) {
            o0 += sh[ww][0]; o1 += sh[ww][1]; o2 += sh[ww][2]; o3 += sh[ww][3];
        }
        out[0] = o0 * inv;
        out[1] = o1 * inv;
        out[2] = o2 * inv;
        out[3] = o3 * inv;
    }
}

// ===========================================================================
extern "C" void kernel_launch(void* const* d_in, const int* in_sizes, int n_in,
                              void* d_out, int out_size, void* d_ws, size_t ws_size,
                              hipStream_t stream)
{
    (void)in_sizes; (void)n_in; (void)out_size; (void)ws_size;
    const float* student = (const float*)d_in[0];
    const float* teacher = (const float*)d_in[1];
    const float* cb      = (const float*)d_in[2];
    const int*   codes   = (const int*)d_in[3];
    float* out = (float*)d_out;
    char* ws = (char*)d_ws;

    // ws layout (~20.1 MB)
    const size_t OFF_APACK = 0;                        // 16 MB (M x 512 fp8)
    const size_t OFF_BPACK = (size_t)M_ * 512;         //  2 MB (K x 512 fp8)
    const size_t OFF_CBN   = OFF_BPACK + (size_t)K_ * 512;       // 16 KB
    const size_t OFF_OUT2  = OFF_CBN + K_ * 4;         //  2 MB (8 x M uint2)
    const size_t OFF_PARTS = OFF_OUT2 + (size_t)8 * M_ * 8;      // 8 KB

    unsigned char* Apack = (unsigned char*)(ws + OFF_APACK);
    unsigned char* Bpack = (unsigned char*)(ws + OFF_BPACK);
    float* cbnb  = (float*)(ws + OFF_CBN);
    uint2* out2  = (uint2*)(ws + OFF_OUT2);
    float* parts = (float*)(ws + OFF_PARTS);

    packA_kernel<<<dim3(T_ / 64, C_ / 64, B_), 256, 0, stream>>>(student, Apack);
    packB_norm_kernel<<<K_ / 4, 256, 0, stream>>>(cb, Bpack, cbnb);
    screen_kernel<<<1024, 256, 0, stream>>>(Apack, Bpack, cbnb, out2);
    loss_kernel<<<M_ / 64, 256, 0, stream>>>(student, teacher, cb, out2, codes, parts);
    final_kernel<<<1, 256, 0, stream>>>(parts, out);
}

// Round 14
// 157.871 us; speedup vs baseline: 1.1681x; 1.1681x over previous
//
#include <hip/hip_runtime.h>
#include <math.h>

#define B_ 16
#define C_ 512
#define T_ 2048
#define K_ 4096
#define M_ (B_*T_)          // 32768 rows
#define MARGIN_ 0.5f

typedef float f32x4    __attribute__((ext_vector_type(4)));
typedef int   int32x4v __attribute__((ext_vector_type(4)));
typedef int   int32x8v __attribute__((ext_vector_type(8)));

static __device__ __forceinline__ unsigned int umin_(unsigned int a, unsigned int b) {
    return a < b ? a : b;
}
static __device__ __forceinline__ unsigned int umax_(unsigned int a, unsigned int b) {
    return a > b ? a : b;
}
// async global->LDS, 16B per lane. LDS dest = wave-uniform base + lane*16.
static __device__ __forceinline__ void gload_lds16(const void* g, void* l) {
    __builtin_amdgcn_global_load_lds(
        (const __attribute__((address_space(1))) unsigned int*)g,
        (__attribute__((address_space(3))) unsigned int*)l,
        16, 0, 0);
}

// float -> OCP e4m3fn, round-nearest-even, 448-saturating, |x|<2^-6 subnormal.
static __device__ __forceinline__ unsigned char f32_to_e4m3(float x) {
    unsigned int u = __float_as_uint(x);
    unsigned int sgn = (u >> 24) & 0x80u;
    unsigned int ax = u & 0x7FFFFFFFu;
    if (ax >= 0x43E00000u) return (unsigned char)(sgn | 0x7Eu);   // >=448 -> 448
    if (ax < 0x3C800000u) {                                       // |x| < 2^-6
        int q = (int)rintf(__uint_as_float(ax) * 512.0f);         // units 2^-9, RNE
        if (q >= 8) return (unsigned char)(sgn | 0x08u);          // -> 2^-6
        return (unsigned char)(sgn | (unsigned)q);
    }
    unsigned int b = ax + 0x7FFFFu + ((ax >> 20) & 1u);           // RNE @ 3 mant bits
    unsigned int e = b >> 23;
    unsigned int m = (b >> 20) & 7u;
    int e4 = (int)e - 127 + 7;
    if (e4 >= 16) return (unsigned char)(sgn | 0x7Eu);            // rounded past 448
    return (unsigned char)(sgn | ((unsigned)e4 << 3) | m);
}

// ---------------------------------------------------------------------------
// pack_A: student (B,C,T) fp32 -> Apack[M][512] fp8 e4m3, PLAIN k-contiguous
// layout (scaled-MFMA lane reads 32 consecutive k-bytes).  64x64 transpose
// tiles through LDS.
// ---------------------------------------------------------------------------
__global__ __launch_bounds__(256) void packA_kernel(
    const float* __restrict__ student, unsigned char* __restrict__ Apack)
{
    __shared__ float ts[64][65];
    const int tid = threadIdx.x;
    const int t0 = blockIdx.x * 64;
    const int c0 = blockIdx.y * 64;
    const int b  = blockIdx.z;

#pragma unroll
    for (int r = 0; r < 4; ++r) {
        int f  = tid + r * 256;
        int i  = f >> 4;                          // c row 0..63
        int j4 = (f & 15) << 2;                   // t col 0..60
        float4 v = *reinterpret_cast<const float4*>(
            student + ((size_t)(b * C_ + c0 + i)) * T_ + (t0 + j4));
        *reinterpret_cast<float4*>(&ts[i][j4]) = v;
    }
    __syncthreads();

#pragma unroll
    for (int r = 0; r < 2; ++r) {
        int f  = tid + r * 256;                   // 0..511
        int j  = f >> 3;                          // t row 0..63
        int pi = f & 7;                           // 8-byte piece
        unsigned long long w = 0ull;
#pragma unroll
        for (int u = 0; u < 8; ++u) {
            unsigned long long byte8 = (unsigned long long)f32_to_e4m3(ts[pi * 8 + u][j]);
            w |= byte8 << (8 * u);
        }
        *reinterpret_cast<unsigned long long*>(
            Apack + (size_t)(b * T_ + t0 + j) * 512 + c0 + pi * 8) = w;
    }
}

// ---------------------------------------------------------------------------
// pack_B + scaled-biased norms: codebook (K,C) fp32 -> Bpack[K][512] fp8
// (plain layout), cbnb256[k] = (||c_k||^2 + 1024) * 256.
// ---------------------------------------------------------------------------
__global__ __launch_bounds__(256) void packB_norm_kernel(
    const float* __restrict__ cb, unsigned char* __restrict__ Bpack,
    float* __restrict__ cbnb256)
{
    int code = blockIdx.x * 4 + (threadIdx.x >> 6);
    int lane = threadIdx.x & 63;
    const float* row = cb + (size_t)code * C_;
    unsigned char* orow = Bpack + (size_t)code * 512;

    int c = lane * 8;
    float4 v0 = *reinterpret_cast<const float4*>(row + c);
    float4 v1 = *reinterpret_cast<const float4*>(row + c + 4);
    float s = v0.x*v0.x + v0.y*v0.y + v0.z*v0.z + v0.w*v0.w
            + v1.x*v1.x + v1.y*v1.y + v1.z*v1.z + v1.w*v1.w;
    unsigned long long w =
          (unsigned long long)f32_to_e4m3(v0.x)
        | ((unsigned long long)f32_to_e4m3(v0.y) << 8)
        | ((unsigned long long)f32_to_e4m3(v0.z) << 16)
        | ((unsigned long long)f32_to_e4m3(v0.w) << 24)
        | ((unsigned long long)f32_to_e4m3(v1.x) << 32)
        | ((unsigned long long)f32_to_e4m3(v1.y) << 40)
        | ((unsigned long long)f32_to_e4m3(v1.z) << 48)
        | ((unsigned long long)f32_to_e4m3(v1.w) << 56);
    *reinterpret_cast<unsigned long long*>(orow + c) = w;

#pragma unroll
    for (int off = 32; off; off >>= 1) s += __shfl_down(s, off);
    if (lane == 0) cbnb256[code] = (s + 1024.0f) * 256.0f;
}

// ---------------------------------------------------------------------------
// MX-fp8 screen in the R12 SHELL: mfma_scale_f32_16x16x128_f8f6f4 with
// scale = E8M0(127) = 1.0 (bit-exact vs non-scaled fp8; call signature and
// lane->k mapping PROVEN by R13's absmax 0.0; 2.27x MFMA rate, m21).
//   score256(m,k) = (||c_k||^2 + 1024)*256 - 512*(z8 . c8)
//   packed        = ((uint)score256 << 12) | k
// Structure = R12 byte-for-byte (proven: conflicts 0, no spill, vmcnt exact):
// 4 x 16 KB buffers, 2-step windows, stage window w+1 post-barrier into the
// pair window w-1 read, vmcnt(0)+barrier per window (loads issued a full
// window earlier -> wait ~free).  ONLY the compute changes: per window,
// 16 ds_read_b128 + 16 scaled MFMAs (vs 32 reads + 64 small MFMAs).
// Window w's two buffers hold k-bytes [0,64) and [64,128) -- exactly one
// 16x16x128 operand span.  Lane (lr,lk): buffer = pair[lk>>1], logical slots
// {(lk&1)*2, +1}, physical = logical ^ key, key=(lr>>1)&3.  Per quarter-wave
// each physical slot gets 4 lanes in row-pairs {+1,+8,+9}; at 64-B row stride
// only +8 aliases banks -> 2-way = free (same arithmetic as R12's measured 0).
// Pack layout: PLAIN (slot permutation only; slot contents = 16 consecutive
// k-bytes).  Grid: flat 1024, XCD-bijective swizzle.  __launch_bounds__(256,2).
// ---------------------------------------------------------------------------
__global__ __launch_bounds__(256, 2) void screen_kernel(
    const unsigned char* __restrict__ Apack,
    const unsigned char* __restrict__ Bpack,
    const float* __restrict__ cbnb256,
    uint2* __restrict__ out2)                      // [8 streams][M]
{
    // [buf 0..3][A/B][128 rows][64 bytes] : 4 x 16 KB = 64 KB
    __shared__ __align__(16) unsigned char lds_tiles[4 * 2 * 128 * 64];
    __shared__ float cbnb_lds[1024];               // this quarter's norms, 4 KB

    const int tid = threadIdx.x;
    const int l   = tid & 63;
    const int wv  = tid >> 6;
    const int wm  = wv >> 1, wn = wv & 1;
    const int lr  = l & 15;
    const int lk  = l >> 4;

    // XCD-bijective block swizzle (1024 blocks, 8 XCDs, 128 each)
    const int bid = blockIdx.x;
    const int wg  = (bid & 7) * 128 + (bid >> 3);
    const int q   = wg & 3;
    const int m0  = (wg >> 2) * 128;

    // ---- cbnb -> LDS (landed by the first window barrier)
    {
        float4 v = reinterpret_cast<const float4*>(cbnb256 + q * 1024)[tid];
        reinterpret_cast<float4*>(cbnb_lds)[tid] = v;
    }

    unsigned int u1[16], u2v[16];
#pragma unroll
    for (int e = 0; e < 16; ++e) { u1[e] = 0xFFFFFFFFu; u2v[e] = 0xFFFFFFFFu; }

    f32x4 acc[4][4];
#pragma unroll
    for (int i = 0; i < 4; ++i)
#pragma unroll
        for (int j = 0; j < 4; ++j) acc[i][j] = (f32x4)0.f;

    // staging lane constants (R12, unchanged): lane l -> row l>>2, lds slot
    // l&3, global source slot (l&3) ^ key(row), key(row) = (row>>1)&3 = (l>>3)&3.
    const int lane_goff = (l >> 2) * 512 + (((l & 3) ^ ((l >> 3) & 3)) * 16);
    const int r0 = wv * 32, r1 = wv * 32 + 16;

    // 4 running stage pointers, positioned at stage step 0.
    const char* pA0 = (const char*)Apack + (size_t)m0 * 512 + lane_goff + (size_t)r0 * 512;
    const char* pA1 = (const char*)Apack + (size_t)m0 * 512 + lane_goff + (size_t)r1 * 512;
    const char* pB0 = (const char*)Bpack + (size_t)q * 524288 + lane_goff + (size_t)r0 * 512;
    const char* pB1 = (const char*)Bpack + (size_t)q * 524288 + lane_goff + (size_t)r1 * 512;

    auto stage_ptr = [&](unsigned bufbase) {
        unsigned char* Ad = &lds_tiles[bufbase];
        unsigned char* Bd = &lds_tiles[bufbase + 8192];
        gload_lds16(pA0, Ad + r0 * 64);
        gload_lds16(pA1, Ad + r1 * 64);
        gload_lds16(pB0, Bd + r0 * 64);
        gload_lds16(pB1, Bd + r1 * 64);
    };
    // advance pointers from stage step (s_next-1) to s_next.
    auto advance = [&](int s_next) {
        bool wrap = (s_next & 7) == 0;             // cc rolled 7 -> 0, ct++
        int dA = wrap ? -448 : 64;
        int dB = wrap ? 65088 : 64;                // 65536 - 448
        pA0 += dA; pA1 += dA; pB0 += dB; pB1 += dB;
    };

    // scaled-MFMA read constants: lane's two physical 16-B slots
    const int key  = (lr >> 1) & 3;
    const int s0b  = ((((lk & 1) * 2)) ^ key) * 16;        // lower 16 k-bytes
    const int s1b  = ((((lk & 1) * 2) | 1) ^ key) * 16;    // upper 16 k-bytes
    const int hsel = (lk >> 1);                            // which buffer of the pair

    // one window = one K=128 slab: bufL holds k[0,64), bufH holds k[64,128)
    auto compute_window = [&](unsigned bufL, unsigned bufH) {
        const unsigned mybuf = hsel ? bufH : bufL;
        int32x8v a[4], bb[4];
#pragma unroll
        for (int i = 0; i < 4; ++i) {
            int ar = wm * 64 + i * 16 + lr;
            const unsigned char* base = &lds_tiles[mybuf + ar * 64];
            int32x4v lo = *reinterpret_cast<const int32x4v*>(base + s0b);
            int32x4v hi = *reinterpret_cast<const int32x4v*>(base + s1b);
            a[i] = __builtin_shufflevector(lo, hi, 0, 1, 2, 3, 4, 5, 6, 7);
        }
#pragma unroll
        for (int j = 0; j < 4; ++j) {
            int br = wn * 64 + j * 16 + lr;
            const unsigned char* base = &lds_tiles[mybuf + 8192 + br * 64];
            int32x4v lo = *reinterpret_cast<const int32x4v*>(base + s0b);
            int32x4v hi = *reinterpret_cast<const int32x4v*>(base + s1b);
            bb[j] = __builtin_shufflevector(lo, hi, 0, 1, 2, 3, 4, 5, 6, 7);
        }
#pragma unroll
        for (int i = 0; i < 4; ++i)
#pragma unroll
            for (int j = 0; j < 4; ++j)
                acc[i][j] = __builtin_amdgcn_mfma_scale_f32_16x16x128_f8f6f4(
                    a[i], bb[j], acc[i][j], 0, 0, 0, 127, 0, 127);
    };

    auto fold = [&](int ct) {
        unsigned int kk4[4];
        float cnb[4];
#pragma unroll
        for (int j = 0; j < 4; ++j) {
            int kl = ct * 128 + wn * 64 + j * 16 + lr;
            kk4[j] = (unsigned int)(q * 1024 + kl);
            cnb[j] = cbnb_lds[kl];
        }
#pragma unroll
        for (int i = 0; i < 4; ++i)
#pragma unroll
            for (int r = 0; r < 4; ++r) {
                int e = i * 4 + r;
                unsigned int p[4];
#pragma unroll
                for (int j = 0; j < 4; ++j) {
                    float s = fmaf(-512.f, acc[i][j][r], cnb[j]);
                    s = fmaxf(s, 0.f);
                    p[j] = ((unsigned int)s << 12) | kk4[j];
                }
                unsigned int mn0 = umin_(p[0], p[1]), mx0 = umax_(p[0], p[1]);
                unsigned int mn1 = umin_(p[2], p[3]), mx1 = umax_(p[2], p[3]);
                unsigned int t0 = umax_(u1[e], mn0);
                u1[e]  = umin_(u1[e], mn0);
                u2v[e] = umin_(umin_(t0, u2v[e]), mx0);
                unsigned int t1 = umax_(u1[e], mn1);
                u1[e]  = umin_(u1[e], mn1);
                u2v[e] = umin_(umin_(t1, u2v[e]), mx1);
            }
#pragma unroll
        for (int i = 0; i < 4; ++i)
#pragma unroll
            for (int j = 0; j < 4; ++j) acc[i][j] = (f32x4)0.f;
    };

    // ---- prologue: stage window 0 (steps 0,1 -> bufs 0,1)
    stage_ptr(0u);        advance(1);
    stage_ptr(16384u);    advance(2);

    // ---- main loop: 32 windows (one K=128 scaled-MFMA slab each)
    for (int w = 0; w < 32; ++w) {
        // window w's 8 loads were issued a full window ago -> wait is ~free.
        asm volatile("s_waitcnt vmcnt(0)" ::: "memory");
        __builtin_amdgcn_s_barrier();

        // stage window w+1 into the pair window w-1 read.
        if (w < 31) {
            int s2 = 2 * w + 2;
            stage_ptr((unsigned)((s2 & 3) * 16384));       advance(s2 + 1);
            stage_ptr((unsigned)(((s2 + 1) & 3) * 16384)); advance(s2 + 2);
        }

        compute_window((unsigned)(((2 * w) & 3) * 16384),
                       (unsigned)(((2 * w + 1) & 3) * 16384));
        if ((w & 3) == 3) fold(w >> 2);
    }

    // ---- cross-lane top-2 merge over the 16 lr lanes
#pragma unroll
    for (int e = 0; e < 16; ++e) {
        unsigned int a1 = u1[e], a2 = u2v[e];
#pragma unroll
        for (int off = 1; off < 16; off <<= 1) {
            unsigned int b1 = (unsigned int)__shfl_xor((int)a1, off);
            unsigned int b2 = (unsigned int)__shfl_xor((int)a2, off);
            unsigned int m1 = umin_(a1, b1);
            a2 = umin_(umax_(a1, b1), umin_(a2, b2));
            a1 = m1;
        }
        u1[e] = a1; u2v[e] = a2;
    }

    if (lr == 0) {
        int cand = q * 2 + wn;
#pragma unroll
        for (int i = 0; i < 4; ++i)
#pragma unroll
            for (int r = 0; r < 4; ++r) {
                int m = m0 + wm * 64 + i * 16 + lk * 4 + r;
                out2[(size_t)cand * M_ + m] = make_uint2(u1[i * 4 + r], u2v[i * 4 + r]);
            }
    }
}

// ---------------------------------------------------------------------------
// fused combine + exact rescore + loss (R11, proven: tail 75 -> 44 us).
// ---------------------------------------------------------------------------
__global__ __launch_bounds__(256) void loss_kernel(
    const float* __restrict__ student, const float* __restrict__ teacher,
    const float* __restrict__ cb, const uint2* __restrict__ out2,
    const int* __restrict__ codes, float* __restrict__ partials)
{
    __shared__ float sh[4][64][5];

    const int l  = threadIdx.x & 63;               // row within block
    const int qw = threadIdx.x >> 6;               // channel quarter (wave id)
    const int m  = blockIdx.x * 64 + l;
    const int b  = m / T_;
    const int t  = m % T_;

    uint2 g = out2[m];
#pragma unroll
    for (int c = 1; c < 8; ++c) {
        uint2 o = out2[(size_t)c * M_ + m];
        unsigned int m1 = umin_(g.x, o.x);
        g.y = umin_(umax_(g.x, o.x), umin_(g.y, o.y));
        g.x = m1;
    }
    const int k1 = (int)(g.x & 0xFFFu);
    const int k2 = (int)(g.y & 0xFFFu);

    const float* sp = student + (size_t)b * C_ * T_ + t;
    const float* tp = teacher + (size_t)b * C_ * T_ + t;
    const float4* c1p = reinterpret_cast<const float4*>(cb + (size_t)k1 * C_);
    const float4* c2p = reinterpret_cast<const float4*>(cb + (size_t)k2 * C_);

    float dp = 0.f, ds1 = 0.f, ds2 = 0.f, dt1 = 0.f, dt2 = 0.f;
    const int c4beg = qw * 32;                     // 32 float4-groups = 128 ch
#pragma unroll 4
    for (int c4 = c4beg; c4 < c4beg + 32; ++c4) {
        float4 cv1 = c1p[c4];
        float4 cv2 = c2p[c4];
        float a0 = tp[(size_t)(c4 * 4 + 0) * T_];
        float a1 = tp[(size_t)(c4 * 4 + 1) * T_];
        float a2 = tp[(size_t)(c4 * 4 + 2) * T_];
        float a3 = tp[(size_t)(c4 * 4 + 3) * T_];
        float p0 = sp[(size_t)(c4 * 4 + 0) * T_];
        float p1 = sp[(size_t)(c4 * 4 + 1) * T_];
        float p2 = sp[(size_t)(c4 * 4 + 2) * T_];
        float p3 = sp[(size_t)(c4 * 4 + 3) * T_];
        float e;
        e = a0 - p0;   dp  = fmaf(e, e, dp);
        e = a1 - p1;   dp  = fmaf(e, e, dp);
        e = a2 - p2;   dp  = fmaf(e, e, dp);
        e = a3 - p3;   dp  = fmaf(e, e, dp);
        e = p0 - cv1.x; ds1 = fmaf(e, e, ds1);
        e = p1 - cv1.y; ds1 = fmaf(e, e, ds1);
        e = p2 - cv1.z; ds1 = fmaf(e, e, ds1);
        e = p3 - cv1.w; ds1 = fmaf(e, e, ds1);
        e = p0 - cv2.x; ds2 = fmaf(e, e, ds2);
        e = p1 - cv2.y; ds2 = fmaf(e, e, ds2);
        e = p2 - cv2.z; ds2 = fmaf(e, e, ds2);
        e = p3 - cv2.w; ds2 = fmaf(e, e, ds2);
        e = a0 - cv1.x; dt1 = fmaf(e, e, dt1);
        e = a1 - cv1.y; dt1 = fmaf(e, e, dt1);
        e = a2 - cv1.z; dt1 = fmaf(e, e, dt1);
        e = a3 - cv1.w; dt1 = fmaf(e, e, dt1);
        e = a0 - cv2.x; dt2 = fmaf(e, e, dt2);
        e = a1 - cv2.y; dt2 = fmaf(e, e, dt2);
        e = a2 - cv2.z; dt2 = fmaf(e, e, dt2);
        e = a3 - cv2.w; dt2 = fmaf(e, e, dt2);
    }
    sh[qw][l][0] = dp;
    sh[qw][l][1] = ds1;
    sh[qw][l][2] = ds2;
    sh[qw][l][3] = dt1;
    sh[qw][l][4] = dt2;
    __syncthreads();

    if (qw == 0) {
        float S0 = 0.f, S1 = 0.f, S2 = 0.f, S3 = 0.f, S4 = 0.f;
#pragma unroll
        for (int w = 0; w < 4; ++w) {
            S0 += sh[w][l][0];
            S1 += sh[w][l][1];
            S2 += sh[w][l][2];
            S3 += sh[w][l][3];
            S4 += sh[w][l][4];
        }
        const int tc = codes[m];
        bool v1 = (k1 != tc), v2 = (k2 != tc);
        bool take2;
        if (!v1)      take2 = true;
        else if (!v2) take2 = false;
        else          take2 = (S2 < S1) || (S2 == S1 && k2 < k1);
        float dn = take2 ? S4 : S3;

        float dpos = sqrtf(S0);
        float dneg = sqrtf(dn);
        float loss = fmaxf(dpos - dneg + MARGIN_, 0.f);
        float ind  = (dneg > dpos + MARGIN_) ? 1.f : 0.f;

        float v0 = loss, vv1 = dpos, vv2 = dneg, vv3 = ind;
#pragma unroll
        for (int off = 32; off; off >>= 1) {
            v0  += __shfl_down(v0, off);
            vv1 += __shfl_down(vv1, off);
            vv2 += __shfl_down(vv2, off);
            vv3 += __shfl_down(vv3, off);
        }
        if (l == 0) {
            partials[blockIdx.x * 4 + 0] = v0;
            partials[blockIdx.x * 4 + 1] = vv1;
            partials[blockIdx.x * 4 + 2] = vv2;
            partials[blockIdx.x * 4 + 3] = vv3;
        }
    }
}

// ---------------------------------------------------------------------------
// final deterministic reduction of 512 partial rows -> 4 means.
// ---------------------------------------------------------------------------
__global__ __launch_bounds__(256) void final_kernel(
    const float* __restrict__ partials, float* __restrict__ out)
{
    __shared__ float sh[4][4];
    int tid = threadIdx.x;                         // 256 threads, 2 rows each
    float s0 = partials[tid * 4 + 0] + partials[(tid + 256) * 4 + 0];
    float s1 = partials[tid * 4 + 1] + partials[(tid + 256) * 4 + 1];
    float s2 = partials[tid * 4 + 2] + partials[(tid + 256) * 4 + 2];
    float s3 = partials[tid * 4 + 3] + partials[(tid + 256) * 4 + 3];
#pragma unroll
    for (int off = 32; off; off >>= 1) {
        s0 += __shfl_down(s0, off);
        s1 += __shfl_down(s1, off);
        s2 += __shfl_down(s2, off);
        s3 += __shfl_down(s3, off);
    }
    int w = tid >> 6, lane = tid & 63;
    if (lane == 0) { sh[w][0] = s0; sh[w][1] = s1; sh[w][2] = s2; sh[w][3] = s3; }
    __syncthreads();
    if (tid == 0) {
        const float inv = 1.0f / (float)M_;
        float o0 = 0.f, o1 = 0.f, o2 = 0.f, o3 = 0.f;
#pragma unroll
        for (int ww = 0; ww < 4; ++ww) {
            o0 += sh[ww][0]; o1 += sh[ww][1]; o2 += sh[ww][2]; o3 += sh[ww][3];
        }
        out[0] = o0 * inv;
        out[1] = o1 * inv;
        out[2] = o2 * inv;
        out[3] = o3 * inv;
    }
}

// ===========================================================================
extern "C" void kernel_launch(void* const* d_in, const int* in_sizes, int n_in,
                              void* d_out, int out_size, void* d_ws, size_t ws_size,
                              hipStream_t stream)
{
    (void)in_sizes; (void)n_in; (void)out_size; (void)ws_size;
    const float* student = (const float*)d_in[0];
    const float* teacher = (const float*)d_in[1];
    const float* cb      = (const float*)d_in[2];
    const int*   codes   = (const int*)d_in[3];
    float* out = (float*)d_out;
    char* ws = (char*)d_ws;

    // ws layout (~20.1 MB)
    const size_t OFF_APACK = 0;                        // 16 MB (M x 512 fp8)
    const size_t OFF_BPACK = (size_t)M_ * 512;         //  2 MB (K x 512 fp8)
    const size_t OFF_CBN   = OFF_BPACK + (size_t)K_ * 512;       // 16 KB
    const size_t OFF_OUT2  = OFF_CBN + K_ * 4;         //  2 MB (8 x M uint2)
    const size_t OFF_PARTS = OFF_OUT2 + (size_t)8 * M_ * 8;      // 8 KB

    unsigned char* Apack = (unsigned char*)(ws + OFF_APACK);
    unsigned char* Bpack = (unsigned char*)(ws + OFF_BPACK);
    float* cbnb  = (float*)(ws + OFF_CBN);
    uint2* out2  = (uint2*)(ws + OFF_OUT2);
    float* parts = (float*)(ws + OFF_PARTS);

    packA_kernel<<<dim3(T_ / 64, C_ / 64, B_), 256, 0, stream>>>(student, Apack);
    packB_norm_kernel<<<K_ / 4, 256, 0, stream>>>(cb, Bpack, cbnb);
    screen_kernel<<<1024, 256, 0, stream>>>(Apack, Bpack, cbnb, out2);
    loss_kernel<<<M_ / 64, 256, 0, stream>>>(student, teacher, cb, out2, codes, parts);
    final_kernel<<<1, 256, 0, stream>>>(parts, out);
}

// Round 15
// 153.867 us; speedup vs baseline: 1.1986x; 1.0260x over previous
//
#include <hip/hip_runtime.h>
#include <math.h>

#define B_ 16
#define C_ 512
#define T_ 2048
#define K_ 4096
#define M_ (B_*T_)          // 32768 rows
#define MARGIN_ 0.5f

typedef float f32x4    __attribute__((ext_vector_type(4)));
typedef int   int32x4v __attribute__((ext_vector_type(4)));
typedef int   int32x8v __attribute__((ext_vector_type(8)));

static __device__ __forceinline__ unsigned int umin_(unsigned int a, unsigned int b) {
    return a < b ? a : b;
}
static __device__ __forceinline__ unsigned int umax_(unsigned int a, unsigned int b) {
    return a > b ? a : b;
}
// async global->LDS, 16B per lane. LDS dest = wave-uniform base + lane*16.
static __device__ __forceinline__ void gload_lds16(const void* g, void* l) {
    __builtin_amdgcn_global_load_lds(
        (const __attribute__((address_space(1))) unsigned int*)g,
        (__attribute__((address_space(3))) unsigned int*)l,
        16, 0, 0);
}

// float -> OCP e4m3fn, round-nearest-even, 448-saturating, |x|<2^-6 subnormal.
static __device__ __forceinline__ unsigned char f32_to_e4m3(float x) {
    unsigned int u = __float_as_uint(x);
    unsigned int sgn = (u >> 24) & 0x80u;
    unsigned int ax = u & 0x7FFFFFFFu;
    if (ax >= 0x43E00000u) return (unsigned char)(sgn | 0x7Eu);   // >=448 -> 448
    if (ax < 0x3C800000u) {                                       // |x| < 2^-6
        int q = (int)rintf(__uint_as_float(ax) * 512.0f);         // units 2^-9, RNE
        if (q >= 8) return (unsigned char)(sgn | 0x08u);          // -> 2^-6
        return (unsigned char)(sgn | (unsigned)q);
    }
    unsigned int b = ax + 0x7FFFFu + ((ax >> 20) & 1u);           // RNE @ 3 mant bits
    unsigned int e = b >> 23;
    unsigned int m = (b >> 20) & 7u;
    int e4 = (int)e - 127 + 7;
    if (e4 >= 16) return (unsigned char)(sgn | 0x7Eu);            // rounded past 448
    return (unsigned char)(sgn | ((unsigned)e4 << 3) | m);
}

// k-group permutation: src byte o (within a 512-B row, 8-B granular) ->
// dest so lane-lk's 32 k-bytes sit at slot lk of step-even (lower 16) and
// slot lk of step-odd (upper 16).  dest = g*128 + h*64 + s*16 + b8*8 where
// o = g*128 + s*32 + h*16 + b8*8.
static __device__ __forceinline__ int kperm8(int o) {
    int g  = o >> 7;
    int r  = o & 127;
    int s  = (r >> 5) & 3;
    int h  = (r >> 4) & 1;
    int b8 = (r >> 3) & 1;
    return g * 128 + h * 64 + s * 16 + b8 * 8;
}

// ---------------------------------------------------------------------------
// pack_A: student (B,C,T) fp32 -> Apack[M][512] fp8 e4m3, k-group-permuted
// layout (kperm8).  64x64 transpose tiles through LDS.
// ---------------------------------------------------------------------------
__global__ __launch_bounds__(256) void packA_kernel(
    const float* __restrict__ student, unsigned char* __restrict__ Apack)
{
    __shared__ float ts[64][65];
    const int tid = threadIdx.x;
    const int t0 = blockIdx.x * 64;
    const int c0 = blockIdx.y * 64;
    const int b  = blockIdx.z;

#pragma unroll
    for (int r = 0; r < 4; ++r) {
        int f  = tid + r * 256;
        int i  = f >> 4;                          // c row 0..63
        int j4 = (f & 15) << 2;                   // t col 0..60
        float4 v = *reinterpret_cast<const float4*>(
            student + ((size_t)(b * C_ + c0 + i)) * T_ + (t0 + j4));
        *reinterpret_cast<float4*>(&ts[i][j4]) = v;
    }
    __syncthreads();

#pragma unroll
    for (int r = 0; r < 2; ++r) {
        int f  = tid + r * 256;                   // 0..511
        int j  = f >> 3;                          // t row 0..63
        int pi = f & 7;                           // 8-byte piece
        unsigned long long w = 0ull;
#pragma unroll
        for (int u = 0; u < 8; ++u) {
            unsigned long long byte8 = (unsigned long long)f32_to_e4m3(ts[pi * 8 + u][j]);
            w |= byte8 << (8 * u);
        }
        *reinterpret_cast<unsigned long long*>(
            Apack + (size_t)(b * T_ + t0 + j) * 512 + kperm8(c0 + pi * 8)) = w;
    }
}

// ---------------------------------------------------------------------------
// pack_B + scaled-biased norms: codebook (K,C) fp32 -> Bpack[K][512] fp8
// (k-group-permuted), cbnb256[k] = (||c_k||^2 + 1024) * 256.
// ---------------------------------------------------------------------------
__global__ __launch_bounds__(256) void packB_norm_kernel(
    const float* __restrict__ cb, unsigned char* __restrict__ Bpack,
    float* __restrict__ cbnb256)
{
    int code = blockIdx.x * 4 + (threadIdx.x >> 6);
    int lane = threadIdx.x & 63;
    const float* row = cb + (size_t)code * C_;
    unsigned char* orow = Bpack + (size_t)code * 512;

    int c = lane * 8;
    float4 v0 = *reinterpret_cast<const float4*>(row + c);
    float4 v1 = *reinterpret_cast<const float4*>(row + c + 4);
    float s = v0.x*v0.x + v0.y*v0.y + v0.z*v0.z + v0.w*v0.w
            + v1.x*v1.x + v1.y*v1.y + v1.z*v1.z + v1.w*v1.w;
    unsigned long long w =
          (unsigned long long)f32_to_e4m3(v0.x)
        | ((unsigned long long)f32_to_e4m3(v0.y) << 8)
        | ((unsigned long long)f32_to_e4m3(v0.z) << 16)
        | ((unsigned long long)f32_to_e4m3(v0.w) << 24)
        | ((unsigned long long)f32_to_e4m3(v1.x) << 32)
        | ((unsigned long long)f32_to_e4m3(v1.y) << 40)
        | ((unsigned long long)f32_to_e4m3(v1.z) << 48)
        | ((unsigned long long)f32_to_e4m3(v1.w) << 56);
    *reinterpret_cast<unsigned long long*>(orow + kperm8(c)) = w;

#pragma unroll
    for (int off = 32; off; off >>= 1) s += __shfl_down(s, off);
    if (lane == 0) cbnb256[code] = (s + 1024.0f) * 256.0f;
}

// ---------------------------------------------------------------------------
// MX-fp8 screen, R12 shell + R12's EXACT fragment-read pattern.
//   mfma_scale_f32_16x16x128_f8f6f4, scale = E8M0(127) = 1.0 (proven R13/R14).
//   score256(m,k) = (||c_k||^2 + 1024)*256 - 512*(z8 . c8)
//   packed        = ((uint)score256 << 12) | k
// R14 post-mortem: its two-slots-per-buffer read pattern measured 8.4e6 bank
// conflicts.  Fix: kperm8 pack permutation puts lane-lk's lower/upper 16
// k-bytes at slot lk of the even/odd 64-B step, so each lane issues ONE
// ds_read_b128 per buffer at slot = lk ^ ((lr>>1)&3) -- byte-identical to
// R12's pattern that measured 0 conflicts for 3 rounds.  Reads/window: 16.
// Shell unchanged: 4 x 16 KB buffers, 2-step windows, stage w+1 post-barrier
// into the pair w-1 read, vmcnt(0)+barrier per window, running pointers,
// XCD-bijective grid swizzle, __launch_bounds__(256,2).
// ---------------------------------------------------------------------------
__global__ __launch_bounds__(256, 2) void screen_kernel(
    const unsigned char* __restrict__ Apack,
    const unsigned char* __restrict__ Bpack,
    const float* __restrict__ cbnb256,
    uint2* __restrict__ out2)                      // [8 streams][M]
{
    // [buf 0..3][A/B][128 rows][64 bytes] : 4 x 16 KB = 64 KB
    __shared__ __align__(16) unsigned char lds_tiles[4 * 2 * 128 * 64];
    __shared__ float cbnb_lds[1024];               // this quarter's norms, 4 KB

    const int tid = threadIdx.x;
    const int l   = tid & 63;
    const int wv  = tid >> 6;
    const int wm  = wv >> 1, wn = wv & 1;
    const int lr  = l & 15;
    const int lk  = l >> 4;

    // XCD-bijective block swizzle (1024 blocks, 8 XCDs, 128 each)
    const int bid = blockIdx.x;
    const int wg  = (bid & 7) * 128 + (bid >> 3);
    const int q   = wg & 3;
    const int m0  = (wg >> 2) * 128;

    // ---- cbnb -> LDS (landed by the first window barrier)
    {
        float4 v = reinterpret_cast<const float4*>(cbnb256 + q * 1024)[tid];
        reinterpret_cast<float4*>(cbnb_lds)[tid] = v;
    }

    unsigned int u1[16], u2v[16];
#pragma unroll
    for (int e = 0; e < 16; ++e) { u1[e] = 0xFFFFFFFFu; u2v[e] = 0xFFFFFFFFu; }

    f32x4 acc[4][4];
#pragma unroll
    for (int i = 0; i < 4; ++i)
#pragma unroll
        for (int j = 0; j < 4; ++j) acc[i][j] = (f32x4)0.f;

    // staging lane constants (R12, unchanged): lane l -> row l>>2, lds slot
    // l&3, global source slot (l&3) ^ key(row), key(row) = (row>>1)&3 = (l>>3)&3.
    const int lane_goff = (l >> 2) * 512 + (((l & 3) ^ ((l >> 3) & 3)) * 16);
    const int r0 = wv * 32, r1 = wv * 32 + 16;

    // 4 running stage pointers, positioned at stage step 0.
    const char* pA0 = (const char*)Apack + (size_t)m0 * 512 + lane_goff + (size_t)r0 * 512;
    const char* pA1 = (const char*)Apack + (size_t)m0 * 512 + lane_goff + (size_t)r1 * 512;
    const char* pB0 = (const char*)Bpack + (size_t)q * 524288 + lane_goff + (size_t)r0 * 512;
    const char* pB1 = (const char*)Bpack + (size_t)q * 524288 + lane_goff + (size_t)r1 * 512;

    auto stage_ptr = [&](unsigned bufbase) {
        unsigned char* Ad = &lds_tiles[bufbase];
        unsigned char* Bd = &lds_tiles[bufbase + 8192];
        gload_lds16(pA0, Ad + r0 * 64);
        gload_lds16(pA1, Ad + r1 * 64);
        gload_lds16(pB0, Bd + r0 * 64);
        gload_lds16(pB1, Bd + r1 * 64);
    };
    // advance pointers from stage step (s_next-1) to s_next.
    auto advance = [&](int s_next) {
        bool wrap = (s_next & 7) == 0;             // cc rolled 7 -> 0, ct++
        int dA = wrap ? -448 : 64;
        int dB = wrap ? 65088 : 64;                // 65536 - 448
        pA0 += dA; pA1 += dA; pB0 += dB; pB1 += dB;
    };

    // R12's proven lane-constant read slot (measured 0 conflicts, R12/R10/R9)
    const int slotoff = (lk ^ ((lr >> 1) & 3)) * 16;

    // one window = one K=128 slab: bufL holds lane's lower 16 k-bytes at
    // slot lk (kperm8), bufH the upper 16 -- one b128 per buffer per operand.
    auto compute_window = [&](unsigned bufL, unsigned bufH) {
        int32x8v a[4], bb[4];
#pragma unroll
        for (int i = 0; i < 4; ++i) {
            int ar = wm * 64 + i * 16 + lr;
            int32x4v lo = *reinterpret_cast<const int32x4v*>(
                &lds_tiles[bufL + ar * 64 + slotoff]);
            int32x4v hi = *reinterpret_cast<const int32x4v*>(
                &lds_tiles[bufH + ar * 64 + slotoff]);
            a[i] = __builtin_shufflevector(lo, hi, 0, 1, 2, 3, 4, 5, 6, 7);
        }
#pragma unroll
        for (int j = 0; j < 4; ++j) {
            int br = wn * 64 + j * 16 + lr;
            int32x4v lo = *reinterpret_cast<const int32x4v*>(
                &lds_tiles[bufL + 8192 + br * 64 + slotoff]);
            int32x4v hi = *reinterpret_cast<const int32x4v*>(
                &lds_tiles[bufH + 8192 + br * 64 + slotoff]);
            bb[j] = __builtin_shufflevector(lo, hi, 0, 1, 2, 3, 4, 5, 6, 7);
        }
#pragma unroll
        for (int i = 0; i < 4; ++i)
#pragma unroll
            for (int j = 0; j < 4; ++j)
                acc[i][j] = __builtin_amdgcn_mfma_scale_f32_16x16x128_f8f6f4(
                    a[i], bb[j], acc[i][j], 0, 0, 0, 127, 0, 127);
    };

    auto fold = [&](int ct) {
        unsigned int kk4[4];
        float cnb[4];
#pragma unroll
        for (int j = 0; j < 4; ++j) {
            int kl = ct * 128 + wn * 64 + j * 16 + lr;
            kk4[j] = (unsigned int)(q * 1024 + kl);
            cnb[j] = cbnb_lds[kl];
        }
#pragma unroll
        for (int i = 0; i < 4; ++i)
#pragma unroll
            for (int r = 0; r < 4; ++r) {
                int e = i * 4 + r;
                unsigned int p[4];
#pragma unroll
                for (int j = 0; j < 4; ++j) {
                    float s = fmaf(-512.f, acc[i][j][r], cnb[j]);
                    s = fmaxf(s, 0.f);
                    p[j] = ((unsigned int)s << 12) | kk4[j];
                }
                unsigned int mn0 = umin_(p[0], p[1]), mx0 = umax_(p[0], p[1]);
                unsigned int mn1 = umin_(p[2], p[3]), mx1 = umax_(p[2], p[3]);
                unsigned int t0 = umax_(u1[e], mn0);
                u1[e]  = umin_(u1[e], mn0);
                u2v[e] = umin_(umin_(t0, u2v[e]), mx0);
                unsigned int t1 = umax_(u1[e], mn1);
                u1[e]  = umin_(u1[e], mn1);
                u2v[e] = umin_(umin_(t1, u2v[e]), mx1);
            }
#pragma unroll
        for (int i = 0; i < 4; ++i)
#pragma unroll
            for (int j = 0; j < 4; ++j) acc[i][j] = (f32x4)0.f;
    };

    // ---- prologue: stage window 0 (steps 0,1 -> bufs 0,1)
    stage_ptr(0u);        advance(1);
    stage_ptr(16384u);    advance(2);

    // ---- main loop: 32 windows (one K=128 scaled-MFMA slab each)
    for (int w = 0; w < 32; ++w) {
        // window w's 8 loads were issued a full window ago -> wait is ~free.
        asm volatile("s_waitcnt vmcnt(0)" ::: "memory");
        __builtin_amdgcn_s_barrier();

        // stage window w+1 into the pair window w-1 read.
        if (w < 31) {
            int s2 = 2 * w + 2;
            stage_ptr((unsigned)((s2 & 3) * 16384));       advance(s2 + 1);
            stage_ptr((unsigned)(((s2 + 1) & 3) * 16384)); advance(s2 + 2);
        }

        compute_window((unsigned)(((2 * w) & 3) * 16384),
                       (unsigned)(((2 * w + 1) & 3) * 16384));
        if ((w & 3) == 3) fold(w >> 2);
    }

    // ---- cross-lane top-2 merge over the 16 lr lanes
#pragma unroll
    for (int e = 0; e < 16; ++e) {
        unsigned int a1 = u1[e], a2 = u2v[e];
#pragma unroll
        for (int off = 1; off < 16; off <<= 1) {
            unsigned int b1 = (unsigned int)__shfl_xor((int)a1, off);
            unsigned int b2 = (unsigned int)__shfl_xor((int)a2, off);
            unsigned int m1 = umin_(a1, b1);
            a2 = umin_(umax_(a1, b1), umin_(a2, b2));
            a1 = m1;
        }
        u1[e] = a1; u2v[e] = a2;
    }

    if (lr == 0) {
        int cand = q * 2 + wn;
#pragma unroll
        for (int i = 0; i < 4; ++i)
#pragma unroll
            for (int r = 0; r < 4; ++r) {
                int m = m0 + wm * 64 + i * 16 + lk * 4 + r;
                out2[(size_t)cand * M_ + m] = make_uint2(u1[i * 4 + r], u2v[i * 4 + r]);
            }
    }
}

// ---------------------------------------------------------------------------
// fused combine + exact rescore + loss (R11, proven: tail 75 -> 44 us).
// ---------------------------------------------------------------------------
__global__ __launch_bounds__(256) void loss_kernel(
    const float* __restrict__ student, const float* __restrict__ teacher,
    const float* __restrict__ cb, const uint2* __restrict__ out2,
    const int* __restrict__ codes, float* __restrict__ partials)
{
    __shared__ float sh[4][64][5];

    const int l  = threadIdx.x & 63;               // row within block
    const int qw = threadIdx.x >> 6;               // channel quarter (wave id)
    const int m  = blockIdx.x * 64 + l;
    const int b  = m / T_;
    const int t  = m % T_;

    uint2 g = out2[m];
#pragma unroll
    for (int c = 1; c < 8; ++c) {
        uint2 o = out2[(size_t)c * M_ + m];
        unsigned int m1 = umin_(g.x, o.x);
        g.y = umin_(umax_(g.x, o.x), umin_(g.y, o.y));
        g.x = m1;
    }
    const int k1 = (int)(g.x & 0xFFFu);
    const int k2 = (int)(g.y & 0xFFFu);

    const float* sp = student + (size_t)b * C_ * T_ + t;
    const float* tp = teacher + (size_t)b * C_ * T_ + t;
    const float4* c1p = reinterpret_cast<const float4*>(cb + (size_t)k1 * C_);
    const float4* c2p = reinterpret_cast<const float4*>(cb + (size_t)k2 * C_);

    float dp = 0.f, ds1 = 0.f, ds2 = 0.f, dt1 = 0.f, dt2 = 0.f;
    const int c4beg = qw * 32;                     // 32 float4-groups = 128 ch
#pragma unroll 4
    for (int c4 = c4beg; c4 < c4beg + 32; ++c4) {
        float4 cv1 = c1p[c4];
        float4 cv2 = c2p[c4];
        float a0 = tp[(size_t)(c4 * 4 + 0) * T_];
        float a1 = tp[(size_t)(c4 * 4 + 1) * T_];
        float a2 = tp[(size_t)(c4 * 4 + 2) * T_];
        float a3 = tp[(size_t)(c4 * 4 + 3) * T_];
        float p0 = sp[(size_t)(c4 * 4 + 0) * T_];
        float p1 = sp[(size_t)(c4 * 4 + 1) * T_];
        float p2 = sp[(size_t)(c4 * 4 + 2) * T_];
        float p3 = sp[(size_t)(c4 * 4 + 3) * T_];
        float e;
        e = a0 - p0;   dp  = fmaf(e, e, dp);
        e = a1 - p1;   dp  = fmaf(e, e, dp);
        e = a2 - p2;   dp  = fmaf(e, e, dp);
        e = a3 - p3;   dp  = fmaf(e, e, dp);
        e = p0 - cv1.x; ds1 = fmaf(e, e, ds1);
        e = p1 - cv1.y; ds1 = fmaf(e, e, ds1);
        e = p2 - cv1.z; ds1 = fmaf(e, e, ds1);
        e = p3 - cv1.w; ds1 = fmaf(e, e, ds1);
        e = p0 - cv2.x; ds2 = fmaf(e, e, ds2);
        e = p1 - cv2.y; ds2 = fmaf(e, e, ds2);
        e = p2 - cv2.z; ds2 = fmaf(e, e, ds2);
        e = p3 - cv2.w; ds2 = fmaf(e, e, ds2);
        e = a0 - cv1.x; dt1 = fmaf(e, e, dt1);
        e = a1 - cv1.y; dt1 = fmaf(e, e, dt1);
        e = a2 - cv1.z; dt1 = fmaf(e, e, dt1);
        e = a3 - cv1.w; dt1 = fmaf(e, e, dt1);
        e = a0 - cv2.x; dt2 = fmaf(e, e, dt2);
        e = a1 - cv2.y; dt2 = fmaf(e, e, dt2);
        e = a2 - cv2.z; dt2 = fmaf(e, e, dt2);
        e = a3 - cv2.w; dt2 = fmaf(e, e, dt2);
    }
    sh[qw][l][0] = dp;
    sh[qw][l][1] = ds1;
    sh[qw][l][2] = ds2;
    sh[qw][l][3] = dt1;
    sh[qw][l][4] = dt2;
    __syncthreads();

    if (qw == 0) {
        float S0 = 0.f, S1 = 0.f, S2 = 0.f, S3 = 0.f, S4 = 0.f;
#pragma unroll
        for (int w = 0; w < 4; ++w) {
            S0 += sh[w][l][0];
            S1 += sh[w][l][1];
            S2 += sh[w][l][2];
            S3 += sh[w][l][3];
            S4 += sh[w][l][4];
        }
        const int tc = codes[m];
        bool v1 = (k1 != tc), v2 = (k2 != tc);
        bool take2;
        if (!v1)      take2 = true;
        else if (!v2) take2 = false;
        else          take2 = (S2 < S1) || (S2 == S1 && k2 < k1);
        float dn = take2 ? S4 : S3;

        float dpos = sqrtf(S0);
        float dneg = sqrtf(dn);
        float loss = fmaxf(dpos - dneg + MARGIN_, 0.f);
        float ind  = (dneg > dpos + MARGIN_) ? 1.f : 0.f;

        float v0 = loss, vv1 = dpos, vv2 = dneg, vv3 = ind;
#pragma unroll
        for (int off = 32; off; off >>= 1) {
            v0  += __shfl_down(v0, off);
            vv1 += __shfl_down(vv1, off);
            vv2 += __shfl_down(vv2, off);
            vv3 += __shfl_down(vv3, off);
        }
        if (l == 0) {
            partials[blockIdx.x * 4 + 0] = v0;
            partials[blockIdx.x * 4 + 1] = vv1;
            partials[blockIdx.x * 4 + 2] = vv2;
            partials[blockIdx.x * 4 + 3] = vv3;
        }
    }
}

// ---------------------------------------------------------------------------
// final deterministic reduction of 512 partial rows -> 4 means.
// ---------------------------------------------------------------------------
__global__ __launch_bounds__(256) void final_kernel(
    const float* __restrict__ partials, float* __restrict__ out)
{
    __shared__ float sh[4][4];
    int tid = threadIdx.x;                         // 256 threads, 2 rows each
    float s0 = partials[tid * 4 + 0] + partials[(tid + 256) * 4 + 0];
    float s1 = partials[tid * 4 + 1] + partials[(tid + 256) * 4 + 1];
    float s2 = partials[tid * 4 + 2] + partials[(tid + 256) * 4 + 2];
    float s3 = partials[tid * 4 + 3] + partials[(tid + 256) * 4 + 3];
#pragma unroll
    for (int off = 32; off; off >>= 1) {
        s0 += __shfl_down(s0, off);
        s1 += __shfl_down(s1, off);
        s2 += __shfl_down(s2, off);
        s3 += __shfl_down(s3, off);
    }
    int w = tid >> 6, lane = tid & 63;
    if (lane == 0) { sh[w][0] = s0; sh[w][1] = s1; sh[w][2] = s2; sh[w][3] = s3; }
    __syncthreads();
    if (tid == 0) {
        const float inv = 1.0f / (float)M_;
        float o0 = 0.f, o1 = 0.f, o2 = 0.f, o3 = 0.f;
#pragma unroll
        for (int ww = 0; ww < 4; ++ww) {
            o0 += sh[ww][0]; o1 += sh[ww][1]; o2 += sh[ww][2]; o3 += sh[ww][3];
        }
        out[0] = o0 * inv;
        out[1] = o1 * inv;
        out[2] = o2 * inv;
        out[3] = o3 * inv;
    }
}

// ===========================================================================
extern "C" void kernel_launch(void* const* d_in, const int* in_sizes, int n_in,
                              void* d_out, int out_size, void* d_ws, size_t ws_size,
                              hipStream_t stream)
{
    (void)in_sizes; (void)n_in; (void)out_size; (void)ws_size;
    const float* student = (const float*)d_in[0];
    const float* teacher = (const float*)d_in[1];
    const float* cb      = (const float*)d_in[2];
    const int*   codes   = (const int*)d_in[3];
    float* out = (float*)d_out;
    char* ws = (char*)d_ws;

    // ws layout (~20.1 MB)
    const size_t OFF_APACK = 0;                        // 16 MB (M x 512 fp8)
    const size_t OFF_BPACK = (size_t)M_ * 512;         //  2 MB (K x 512 fp8)
    const size_t OFF_CBN   = OFF_BPACK + (size_t)K_ * 512;       // 16 KB
    const size_t OFF_OUT2  = OFF_CBN + K_ * 4;         //  2 MB (8 x M uint2)
    const size_t OFF_PARTS = OFF_OUT2 + (size_t)8 * M_ * 8;      // 8 KB

    unsigned char* Apack = (unsigned char*)(ws + OFF_APACK);
    unsigned char* Bpack = (unsigned char*)(ws + OFF_BPACK);
    float* cbnb  = (float*)(ws + OFF_CBN);
    uint2* out2  = (uint2*)(ws + OFF_OUT2);
    float* parts = (float*)(ws + OFF_PARTS);

    packA_kernel<<<dim3(T_ / 64, C_ / 64, B_), 256, 0, stream>>>(student, Apack);
    packB_norm_kernel<<<K_ / 4, 256, 0, stream>>>(cb, Bpack, cbnb);
    screen_kernel<<<1024, 256, 0, stream>>>(Apack, Bpack, cbnb, out2);
    loss_kernel<<<M_ / 64, 256, 0, stream>>>(student, teacher, cb, out2, codes, parts);
    final_kernel<<<1, 256, 0, stream>>>(parts, out);
}